// Round 17
// baseline (29.411 us; speedup 1.0000x reference)
//
#include <hip/hip_runtime.h>

#define Hd    256
#define OUTD  10
#define DDEP  10
#define KSTR  12
#define TLEN  8192
#define NTHR  1024
#define NBLK  256
#define TILE  2048

typedef __attribute__((ext_vector_type(8))) short bf16x8;
typedef __attribute__((ext_vector_type(4))) float f32x4;

__device__ __forceinline__ int ph(int j) { return j + (j >> 5); }

// bf16 round-to-nearest-even helpers (no NaN in this data)
__device__ __forceinline__ unsigned bfr(float x) {
    unsigned u = __float_as_uint(x);
    return (u + 0x7FFFu + ((u >> 16) & 1u)) >> 16;
}
__device__ __forceinline__ unsigned bfpk(float lo, float hi) {
    unsigned uh = __float_as_uint(hi);
    unsigned h  = (uh + 0x7FFFu + ((uh >> 16) & 1u)) & 0xFFFF0000u;
    return bfr(lo) | h;
}

// LDS float/u32 offsets (W2h eliminated -> 112 KB total):
//  [0, 22528)      yb transpose buffer (epilogue)
//  [22528, 23040)  Vs2 [2][256] fp32 v ping-pong
//  [23040, 25600)  W3s [10][256]
//  [25600, 25856)  Vbf [2][128] u32 bf16-pair ping-pong
//  [25856, 25984)  Ks [10][12] (+pad)
//  [25984, ...)    xs conv window (swizzled)
#define OFF_YB  0
#define OFF_VS  22528
#define OFF_W3  23040
#define OFF_VBF 25600
#define OFF_KS  25856
#define OFF_XS  25984
#define XS_LOG  (TILE + DDEP)
#define SMEM_FLOATS (OFF_XS + XS_LOG + (XS_LOG >> 5) + 4)   // ~112.4 KB

__global__ __launch_bounds__(NTHR, 1) void fused_rnn_kernel(
    const float* __restrict__ x, const float* __restrict__ w1g,
    const float* __restrict__ W2, const float* __restrict__ W3,
    float* __restrict__ y)
{
    __shared__ float smem[SMEM_FLOATS];
    float* yb  = smem + OFF_YB;
    float* Vs2 = smem + OFF_VS;
    float* W3s = smem + OFF_W3;
    unsigned* Vbf = (unsigned*)(smem + OFF_VBF);
    float* Ks  = smem + OFF_KS;
    float* xs  = smem + OFF_XS;

    const int tid = threadIdx.x;
    const int bid = blockIdx.x;
    const int b   = bid >> 2;
    const int t0  = (bid & 3) * TILE;
    const float* xb = x + b * TLEN;

    const int w = tid >> 6, l = tid & 63;

    // ---- role-split staging ----
    // Chain waves (0-7): A-frags DIRECT global->VGPR. For fixed (rt,kt) the wave
    // reads 16 rows x 128 B contiguous (4 lanes x 32 B) -> full line utilization.
    bf16x8 Afr[2][8];
    if (w < 8) {
        #pragma unroll
        for (int rt = 0; rt < 2; ++rt) {
            const float* rp = W2 + (32 * w + 16 * rt + (l & 15)) * Hd + (l >> 4) * 8;
            #pragma unroll
            for (int kt = 0; kt < 8; ++kt) {
                const float4 pa = *(const float4*)(rp + kt * 32);
                const float4 pb = *(const float4*)(rp + kt * 32 + 4);
                Afr[rt][kt] = __builtin_bit_cast(bf16x8,
                    make_int4((int)bfpk(pa.x, pa.y), (int)bfpk(pa.z, pa.w),
                              (int)bfpk(pb.x, pb.y), (int)bfpk(pb.z, pb.w)));
            }
        }
        if (tid < 128) Vbf[tid] = bfpk(w1g[2 * tid], w1g[2 * tid + 1]);
        if (tid < 256) Vs2[tid] = w1g[tid];            // fp32 v0 (buffer 0)
    } else {
        // K-waves (8-15): stage xs (swizzled), W3s, K pads
        const int t2 = tid - 512;
        for (int j = t2; j < XS_LOG; j += 512) {
            const int g = t0 - DDEP + j;
            xs[ph(j)] = (g >= 0) ? xb[g] : 0.0f;
        }
        for (int i = t2; i < OUTD * Hd; i += 512) W3s[i] = W3[i];
        if (t2 < 2 * DDEP) Ks[(t2 >> 1) * KSTR + 10 + (t2 & 1)] = 0.0f;
    }
    __syncthreads();

    // ---- fused loop: chain iter d (waves 0-7) || K[d]-dots (waves 8-15) ----
    #pragma unroll 1
    for (int d = 0; d < DDEP - 1; ++d) {
        if (w < 8) {
            const unsigned* vbf = Vbf + (d & 1) * 128;
            f32x4 acc0 = {0.f, 0.f, 0.f, 0.f};
            f32x4 acc1 = {0.f, 0.f, 0.f, 0.f};
            #pragma unroll
            for (int kt = 0; kt < 8; ++kt) {
                const bf16x8 Bfr = __builtin_bit_cast(bf16x8,
                    *(const int4*)&vbf[kt * 16 + (l >> 4) * 4]);
                acc0 = __builtin_amdgcn_mfma_f32_16x16x32_bf16(Afr[0][kt], Bfr, acc0, 0, 0, 0);
                acc1 = __builtin_amdgcn_mfma_f32_16x16x32_bf16(Afr[1][kt], Bfr, acc1, 0, 0, 0);
            }
            // C layout: col = lane&15, row = (lane>>4)*4 + reg (m89-verified)
            if ((l & 15) == 0) {
                const int g  = l >> 4;
                const int r0 = 32 * w + 4 * g;
                const int r1 = r0 + 16;
                float* vdst = Vs2 + ((d + 1) & 1) * Hd;
                *(f32x4*)&vdst[r0] = acc0;
                *(f32x4*)&vdst[r1] = acc1;
                unsigned* dst = Vbf + ((d + 1) & 1) * 128;
                *(uint2*)&dst[r0 >> 1] =
                    make_uint2(bfpk(acc0.x, acc0.y), bfpk(acc0.z, acc0.w));
                *(uint2*)&dst[r1 >> 1] =
                    make_uint2(bfpk(acc1.x, acc1.y), bfpk(acc1.z, acc1.w));
            }
        } else {
            // K[d][o] = W3[o] . v_d (fp32, from ping-pong slot written last iter)
            const float4 vv = ((const float4*)(Vs2 + (d & 1) * Hd))[l];
            int o = w - 8;
            #pragma unroll 1
            for (int rep = 0; rep < 2; ++rep) {
                if (o < OUTD) {
                    const float4 wv = ((const float4*)(W3s + o * Hd))[l];
                    float p = fmaf(wv.x, vv.x,
                              fmaf(wv.y, vv.y,
                              fmaf(wv.z, vv.z, wv.w * vv.w)));
                    p += __shfl_xor(p, 1);  p += __shfl_xor(p, 2);
                    p += __shfl_xor(p, 4);  p += __shfl_xor(p, 8);
                    p += __shfl_xor(p, 16); p += __shfl_xor(p, 32);
                    if (l == 0) Ks[d * KSTR + o] = p;
                }
                o = (w - 8) + 8;          // waves 8,9 also cover o = 8,9
                if (w - 8 >= 2) break;
            }
        }
        __syncthreads();
    }

    // ---- K[DDEP-1] (last v slot) ----
    if (w >= 8) {
        const int d = DDEP - 1;
        const float4 vv = ((const float4*)(Vs2 + (d & 1) * Hd))[l];
        int o = w - 8;
        #pragma unroll 1
        for (int rep = 0; rep < 2; ++rep) {
            if (o < OUTD) {
                const float4 wv = ((const float4*)(W3s + o * Hd))[l];
                float p = fmaf(wv.x, vv.x,
                          fmaf(wv.y, vv.y,
                          fmaf(wv.z, vv.z, wv.w * vv.w)));
                p += __shfl_xor(p, 1);  p += __shfl_xor(p, 2);
                p += __shfl_xor(p, 4);  p += __shfl_xor(p, 8);
                p += __shfl_xor(p, 16); p += __shfl_xor(p, 32);
                if (l == 0) Ks[d * KSTR + o] = p;
            }
            o = (w - 8) + 8;
            if (w - 8 >= 2) break;
        }
    }
    __syncthreads();

    // ---- causal FIR: 2 consecutive positions per thread ----
    const int ub = tid * 2;
    float acc0[OUTD], acc1[OUTD];
    #pragma unroll
    for (int o = 0; o < OUTD; ++o) { acc0[o] = 0.f; acc1[o] = 0.f; }

    float wn0 = xs[ph(ub + DDEP)];
    float wn1 = xs[ph(ub + DDEP + 1)];

    #pragma unroll
    for (int d = 0; d < DDEP; ++d) {
        const float4 kA = *(const float4*)&Ks[d * KSTR];
        const float4 kB = *(const float4*)&Ks[d * KSTR + 4];
        const float2 kC = *(const float2*)&Ks[d * KSTR + 8];
        acc0[0] = fmaf(kA.x, wn0, acc0[0]);  acc1[0] = fmaf(kA.x, wn1, acc1[0]);
        acc0[1] = fmaf(kA.y, wn0, acc0[1]);  acc1[1] = fmaf(kA.y, wn1, acc1[1]);
        acc0[2] = fmaf(kA.z, wn0, acc0[2]);  acc1[2] = fmaf(kA.z, wn1, acc1[2]);
        acc0[3] = fmaf(kA.w, wn0, acc0[3]);  acc1[3] = fmaf(kA.w, wn1, acc1[3]);
        acc0[4] = fmaf(kB.x, wn0, acc0[4]);  acc1[4] = fmaf(kB.x, wn1, acc1[4]);
        acc0[5] = fmaf(kB.y, wn0, acc0[5]);  acc1[5] = fmaf(kB.y, wn1, acc1[5]);
        acc0[6] = fmaf(kB.z, wn0, acc0[6]);  acc1[6] = fmaf(kB.z, wn1, acc1[6]);
        acc0[7] = fmaf(kB.w, wn0, acc0[7]);  acc1[7] = fmaf(kB.w, wn1, acc1[7]);
        acc0[8] = fmaf(kC.x, wn0, acc0[8]);  acc1[8] = fmaf(kC.x, wn1, acc1[8]);
        acc0[9] = fmaf(kC.y, wn0, acc0[9]);  acc1[9] = fmaf(kC.y, wn1, acc1[9]);
        wn1 = wn0;
        wn0 = xs[ph(ub + DDEP - 1 - d)];
    }

    // ---- transpose via LDS (stride 11), then coalesced nontemporal stores ----
    #pragma unroll
    for (int o = 0; o < OUTD; ++o) {
        yb[ub * 11 + o]      = acc0[o];
        yb[ub * 11 + 11 + o] = acc1[o];
    }
    __syncthreads();

    float* yg = y + ((size_t)b * TLEN + t0) * OUTD;
    #pragma unroll
    for (int pass = 0; pass < 5; ++pass) {
        const int l2 = (pass * NTHR + tid) * 4;
        f32x4 v;
        v.x = yb[l2     + (l2    ) / 10];
        v.y = yb[l2 + 1 + (l2 + 1) / 10];
        v.z = yb[l2 + 2 + (l2 + 2) / 10];
        v.w = yb[l2 + 3 + (l2 + 3) / 10];
        __builtin_nontemporal_store(v, (f32x4*)(yg + l2));
    }
}

extern "C" void kernel_launch(void* const* d_in, const int* in_sizes, int n_in,
                              void* d_out, int out_size, void* d_ws, size_t ws_size,
                              hipStream_t stream)
{
    const float* x  = (const float*)d_in[0];   // (64, 8192)
    const float* w1 = (const float*)d_in[1];   // (256, 1) contiguous
    const float* W2 = (const float*)d_in[2];   // (256, 256)
    const float* W3 = (const float*)d_in[3];   // (10, 256)
    float* y  = (float*)d_out;

    fused_rnn_kernel<<<NBLK, dim3(NTHR), 0, stream>>>(x, w1, W2, W3, y);
}